// Round 11
// baseline (78.583 us; speedup 1.0000x reference)
//
#include <hip/hip_runtime.h>
#include <hip/hip_bf16.h>

typedef __attribute__((ext_vector_type(8))) short bf16x8;
typedef __attribute__((ext_vector_type(4))) float f32x4;

#define D_DIM 256   // input feature dim
#define H_DIM 128   // hidden dim per branch
#define NXCD 8      // XCDs on MI355X

// RNE float->bf16 (bit pattern)
__device__ inline ushort f2bf(float f) {
    union { float f; unsigned u; } a; a.f = f;
    unsigned r = a.u + 0x7fffu + ((a.u >> 16) & 1u);
    return (ushort)(r >> 16);
}

// K0: build Wt bf16 [hcat][k]; zero the 8 per-XCD accumulator copies.
__global__ void k0_init(const float* __restrict__ W_nb, const float* __restrict__ W_self,
                        ushort* __restrict__ Wt, float* __restrict__ priv, int PN) {
    int i = blockIdx.x * 256 + threadIdx.x;
    if (i < 2 * H_DIM * D_DIM) {
        int sel = i >> 15;
        int r   = i & 32767;
        int k   = r >> 7;
        int h   = r & 127;
        const float* W = sel ? W_self : W_nb;
        Wt[(sel * H_DIM + h) * D_DIM + k] = f2bf(W[k * H_DIM + h]);
    }
    if (i < PN) priv[i] = 0.f;
}

// K1: persistent-B fused GEMM with double-buffered A staging.
//   grid = 256 x 512 thr (8 waves). Wave w: rh=w>>2 row half, cg=w&3 col group.
//   B fragments (128 VGPR) loaded once; per tile: issue next tile's global loads,
//   MFMA current LDS buffer, then convert+write next buffer (latency hidden).
__global__ __launch_bounds__(512, 2) void k1_gemm(
    const float* __restrict__ x, const ushort* __restrict__ Wt,
    const float* __restrict__ b_nb, const float* __restrict__ b_self,
    const float* __restrict__ W_att,
    float* __restrict__ g_nb, float* __restrict__ g_self, int N, int ntiles)
{
    __shared__ __align__(16) ushort A_lds[2][64][264];   // 2 x 33.8KB
    __shared__ float part[2][2][64];

    const int t    = threadIdx.x;
    const int lane = t & 63;
    const int w    = t >> 6;
    const int rh   = w >> 2;
    const int cg   = w & 3;
    const int br   = cg >> 1;
    const int ch   = cg & 1;
    const int li   = lane & 15;
    const int grp  = lane >> 4;
    const int G    = gridDim.x;

    float bias[4], aw[4];
    #pragma unroll
    for (int ni = 0; ni < 4; ni++) {
        int hh = ch * 64 + ni * 16 + li;
        bias[ni] = br ? b_self[hh] : b_nb[hh];
        aw[ni]   = W_att[br * H_DIM + hh];
    }

    bf16x8 Bf[4][8];
    #pragma unroll
    for (int ni = 0; ni < 4; ni++)
        #pragma unroll
        for (int ks = 0; ks < 8; ks++)
            Bf[ni][ks] = *reinterpret_cast<const bf16x8*>(
                Wt + (size_t)(cg * 64 + ni * 16 + li) * D_DIM + ks * 32 + grp * 8);

    const int sr = t >> 3;          // 0..63
    const int sc = t & 7;           // 0..7

    int rt  = blockIdx.x;
    if (rt >= ntiles) return;
    int cur = 0;

    // ---- prologue: stage first tile into buf 0 ----
    {
        const int gr = rt * 64 + sr;
        const bool v = gr < N;
        const float4* src = reinterpret_cast<const float4*>(x + (size_t)gr * D_DIM);
        #pragma unroll
        for (int j = 0; j < 8; j++) {
            int c4 = sc + j * 8;
            ushort4 o;
            if (v) {
                float4 f = src[c4];
                o.x = f2bf(f.x); o.y = f2bf(f.y); o.z = f2bf(f.z); o.w = f2bf(f.w);
            } else { o.x = 0; o.y = 0; o.z = 0; o.w = 0; }
            *reinterpret_cast<ushort4*>(&A_lds[0][sr][c4 * 4]) = o;
        }
    }
    __syncthreads();

    for (; rt < ntiles; rt += G, cur ^= 1) {
        const int row0 = rt * 64;
        const int nxt  = rt + G;
        const bool have_next = nxt < ntiles;

        // ---- issue next tile's global loads early (latency under MFMA) ----
        float4 st[8];
        bool nv = false;
        if (have_next) {
            const int gr = nxt * 64 + sr;
            nv = gr < N;
            const float4* src = reinterpret_cast<const float4*>(x + (size_t)gr * D_DIM);
            if (nv) {
                #pragma unroll
                for (int j = 0; j < 8; j++) st[j] = src[sc + j * 8];
            }
        }

        // ---- MFMA over K=256 from A_lds[cur] ----
        f32x4 acc[2][4];
        #pragma unroll
        for (int mi = 0; mi < 2; mi++)
            #pragma unroll
            for (int ni = 0; ni < 4; ni++) acc[mi][ni] = f32x4{0.f, 0.f, 0.f, 0.f};

        #pragma unroll
        for (int ks = 0; ks < 8; ks++) {
            bf16x8 af0 = *reinterpret_cast<const bf16x8*>(&A_lds[cur][rh * 32 + li][ks * 32 + grp * 8]);
            bf16x8 af1 = *reinterpret_cast<const bf16x8*>(&A_lds[cur][rh * 32 + 16 + li][ks * 32 + grp * 8]);
            #pragma unroll
            for (int ni = 0; ni < 4; ni++) {
                acc[0][ni] = __builtin_amdgcn_mfma_f32_16x16x32_bf16(af0, Bf[ni][ks], acc[0][ni], 0, 0, 0);
                acc[1][ni] = __builtin_amdgcn_mfma_f32_16x16x32_bf16(af1, Bf[ni][ks], acc[1][ni], 0, 0, 0);
            }
        }

        // ---- write staged next tile to the other buffer ----
        if (have_next) {
            #pragma unroll
            for (int j = 0; j < 8; j++) {
                int c4 = sc + j * 8;
                ushort4 o;
                if (nv) {
                    float4 f = st[j];
                    o.x = f2bf(f.x); o.y = f2bf(f.y); o.z = f2bf(f.z); o.w = f2bf(f.w);
                } else { o.x = 0; o.y = 0; o.z = 0; o.w = 0; }
                *reinterpret_cast<ushort4*>(&A_lds[cur ^ 1][sr][c4 * 4]) = o;
            }
        }

        // ---- epilogue: bias + relu + weighted col-sum ----
        float p[2][4];
        #pragma unroll
        for (int mi = 0; mi < 2; mi++)
            #pragma unroll
            for (int r4 = 0; r4 < 4; r4++) p[mi][r4] = 0.f;
        #pragma unroll
        for (int ni = 0; ni < 4; ni++)
            #pragma unroll
            for (int mi = 0; mi < 2; mi++)
                #pragma unroll
                for (int r4 = 0; r4 < 4; r4++) {
                    float y = acc[mi][ni][r4] + bias[ni];
                    y = y > 0.f ? y : 0.f;
                    p[mi][r4] += y * aw[ni];
                }
        #pragma unroll
        for (int mi = 0; mi < 2; mi++)
            #pragma unroll
            for (int r4 = 0; r4 < 4; r4++) {
                float v = p[mi][r4];
                #pragma unroll
                for (int m = 1; m < 16; m <<= 1) v += __shfl_xor(v, m);
                if (li == 0)
                    part[br][ch][rh * 32 + mi * 16 + grp * 4 + r4] = v;
            }
        __syncthreads();   // part visible AND next buffer staged

        if (t < 128) {
            int b_ = t >> 6, lr = t & 63;
            int gr = row0 + lr;
            if (gr < N) {
                float val = part[b_][0][lr] + part[b_][1][lr];
                if (b_) g_self[gr] = val; else g_nb[gr] = val;
            }
        }
        __syncthreads();   // part consumed before next iteration overwrites
    }
}

// K2: edge pass — 4 edges/thread, vectorized streams, 4 in-flight gathers,
// predicated workgroup-scope atomics into the XCD-private copy.
__global__ __launch_bounds__(256) void k2_edge1(
    const int* __restrict__ row, const int* __restrict__ col,
    const float* __restrict__ values, const float* __restrict__ noise,
    const float* __restrict__ g_nb, const float* __restrict__ g_self,
    const float* __restrict__ b_att,
    float* __restrict__ mv_out, float* __restrict__ priv, int N, int E)
{
    unsigned xcd;
    asm volatile("s_getreg_b32 %0, hwreg(HW_REG_XCC_ID)" : "=s"(xcd));
    float* myp = priv + (size_t)(xcd & (NXCD - 1)) * N;

    int i = (blockIdx.x * 256 + threadIdx.x) * 4;
    if (i >= E) return;
    const float ba = b_att[0];
    if (i + 3 < E) {
        int4   r4 = *reinterpret_cast<const int4*>(row + i);
        int4   c4 = *reinterpret_cast<const int4*>(col + i);
        float4 v4 = *reinterpret_cast<const float4*>(values + i);
        float4 u4 = *reinterpret_cast<const float4*>(noise + i);
        int   rr[4] = { r4.x, r4.y, r4.z, r4.w };
        int   cc[4] = { c4.x, c4.y, c4.z, c4.w };
        float vv[4] = { v4.x, v4.y, v4.z, v4.w };
        float uu[4] = { u4.x, u4.y, u4.z, u4.w };
        float gn[4], gs[4];
        #pragma unroll
        for (int j = 0; j < 4; j++) { gn[j] = g_nb[rr[j]]; gs[j] = g_self[cc[j]]; }
        float m[4];
        #pragma unroll
        for (int j = 0; j < 4; j++) {
            float u    = uu[j] + 1e-7f;
            float la   = gn[j] + gs[j] + ba;
            float gate = u / (u + (1.f - u) * __expf(-la));
            float mask = fminf(fmaxf(gate * 1.6f - 0.5f, 0.f), 1.f);
            m[j] = vv[j] * mask;
        }
        *reinterpret_cast<float4*>(mv_out + i) = make_float4(m[0], m[1], m[2], m[3]);
        #pragma unroll
        for (int j = 0; j < 4; j++)
            if (m[j] != 0.f)
                __hip_atomic_fetch_add(myp + rr[j], m[j], __ATOMIC_RELAXED,
                                       __HIP_MEMORY_SCOPE_WORKGROUP);
    } else {
        for (int j = 0; j < 4 && i + j < E; j++) {
            int e = i + j;
            int   r = row[e], c = col[e];
            float u = noise[e] + 1e-7f;
            float la = g_nb[r] + g_self[c] + ba;
            float gate = u / (u + (1.f - u) * __expf(-la));
            float mask = fminf(fmaxf(gate * 1.6f - 0.5f, 0.f), 1.f);
            float m = values[e] * mask;
            mv_out[e] = m;
            if (m != 0.f)
                __hip_atomic_fetch_add(myp + r, m, __ATOMIC_RELAXED,
                                       __HIP_MEMORY_SCOPE_WORKGROUP);
        }
    }
}

// K2b: dis[n] = rsqrt(1e-10 + sum over the 8 XCD copies).
__global__ __launch_bounds__(256) void k2b_reduce(
    const float* __restrict__ priv, float* __restrict__ dis, int N)
{
    int n = blockIdx.x * 256 + threadIdx.x;
    if (n >= N) return;
    float s = 1e-10f;
    #pragma unroll
    for (int p = 0; p < NXCD; p++) s += priv[(size_t)p * N + n];
    dis[n] = rsqrtf(s);
}

// K3: symmetric degree normalization — 4 edges/thread, vectorized.
__global__ __launch_bounds__(256) void k3_edge2(
    const int* __restrict__ row, const int* __restrict__ col,
    float* __restrict__ out, const float* __restrict__ dis, int E)
{
    int i = (blockIdx.x * 256 + threadIdx.x) * 4;
    if (i >= E) return;
    if (i + 3 < E) {
        int4   r4 = *reinterpret_cast<const int4*>(row + i);
        int4   c4 = *reinterpret_cast<const int4*>(col + i);
        float4 m4 = *reinterpret_cast<const float4*>(out + i);
        float4 o;
        o.x = m4.x * dis[r4.x] * dis[c4.x];
        o.y = m4.y * dis[r4.y] * dis[c4.y];
        o.z = m4.z * dis[r4.z] * dis[c4.z];
        o.w = m4.w * dis[r4.w] * dis[c4.w];
        *reinterpret_cast<float4*>(out + i) = o;
    } else {
        for (int j = 0; j < 4 && i + j < E; j++) {
            int e = i + j;
            out[e] = out[e] * dis[row[e]] * dis[col[e]];
        }
    }
}

extern "C" void kernel_launch(void* const* d_in, const int* in_sizes, int n_in,
                              void* d_out, int out_size, void* d_ws, size_t ws_size,
                              hipStream_t stream) {
    const float* x      = (const float*)d_in[0];
    const float* W_nb   = (const float*)d_in[1];
    const float* b_nb   = (const float*)d_in[2];
    const float* W_self = (const float*)d_in[3];
    const float* b_self = (const float*)d_in[4];
    const float* W_att  = (const float*)d_in[5];
    const float* b_att  = (const float*)d_in[6];
    const float* values = (const float*)d_in[7];
    const float* noise  = (const float*)d_in[8];
    const int*   row    = (const int*)d_in[9];
    const int*   col    = (const int*)d_in[10];

    const int N = in_sizes[0] / D_DIM;
    const int E = in_sizes[7];
    float* out = (float*)d_out;

    char* ws = (char*)d_ws;
    ushort* Wt     = (ushort*)ws;                       // 131072 B
    float*  g_nb   = (float*)(ws + 131072);             // N
    float*  g_self = g_nb + N;                          // N
    float*  dis    = g_self + N;                        // N
    float*  priv   = dis + N;                           // NXCD * N

    const int PN = NXCD * N;

    int init_n = 2 * H_DIM * D_DIM;
    if (PN > init_n) init_n = PN;
    k0_init<<<(init_n + 255) / 256, 256, 0, stream>>>(W_nb, W_self, Wt, priv, PN);

    const int ntiles = (N + 63) / 64;
    k1_gemm<<<256, 512, 0, stream>>>(x, Wt, b_nb, b_self, W_att, g_nb, g_self, N, ntiles);

    int eb4 = ((E + 3) / 4 + 255) / 256;
    k2_edge1<<<eb4, 256, 0, stream>>>(row, col, values, noise, g_nb, g_self, b_att,
                                      out, priv, N, E);
    k2b_reduce<<<(N + 255) / 256, 256, 0, stream>>>(priv, dis, N);
    k3_edge2<<<eb4, 256, 0, stream>>>(row, col, out, dis, E);
}